// Round 7
// baseline (82.060 us; speedup 1.0000x reference)
//
#include <hip/hip_runtime.h>
#include <hip/hip_bf16.h>
#include <stdint.h>

// Recommender: B=4096 users, L=200 history, D=64 emb, F=100000 films.
// Single fused kernel, one 512-thread block per user.
// Pass 1 (coalesced): wave w owns rows l = w+8i, lane = dim d; 16-bit sortable
//   keys pair-packed to LDS keys[d][w*28+i]; min/max/sum partials to red3.
// Pass 2: select-lane (sub,dloc) reads 28 keys as 7 b64 (layout feeds the dual
//   16x16 bit-transpose directly); bit-serial popc median select (verified).
// MLP fused, packed-f32 (v_pk_fma_f32), j-pair decomposition; the ue
// L2-normalization is folded into the h1 combine: h1 = b1 + rn*A + (1-rn)*B.

#define B_ 4096
#define L_ 200
#define D_ 64
#define LPAD 224      // 8 * max cmax4
#define KP_U16 228    // per-dim key pitch in u16 (456 B)

typedef float v2f __attribute__((ext_vector_type(2)));

__device__ __forceinline__ v2f pk_fma(v2f a, v2f b, v2f c) {
  v2f d;
  asm("v_pk_fma_f32 %0, %1, %2, %3" : "=v"(d) : "v"(a), "v"(b), "v"(c));
  return d;
}

__global__ __launch_bounds__(512) void fused_kernel(
    const int* __restrict__ film_hist,
    const float* __restrict__ ratings,
    const int* __restrict__ lengths,
    const int* __restrict__ film_indices,
    const float* __restrict__ emb,
    const float* __restrict__ W1, const float* __restrict__ b1,
    const float* __restrict__ W2, const float* __restrict__ b2,
    const float* __restrict__ W3, const float* __restrict__ b3,
    float* __restrict__ out)
{
  __shared__ int   hist_s[LPAD];
  __shared__ float rat_s[LPAD];
  __shared__ float red[8];
  __shared__ float xraw[320];                // [ue_raw(256) | fe(64)]
  __shared__ float red3[3*512];              // min/max/sum partials [3][8][64]
  __shared__ union {
    uint16_t keys[D_*KP_U16];                // 29184 B, live until select done
    struct { v2f phA[512]; v2f phB[128]; float h1s[128]; } m;  // MLP phase
  } sh;

  const int b = blockIdx.x;
  const int t = threadIdx.x;
  const int w = t >> 6;                      // wave id
  const int lane = t & 63;                   // pass1: dim d
  const int n = lengths[b];
  const int cmax  = (n + 7) >> 3;            // <=25, block-uniform
  const int cmax4 = (cmax + 3) & ~3;         // multiple of 4, <=28

  // clamped staging (covers padding in one pass); fe into xraw[256..319]
  float r = 0.f;
  if (t < LPAD) {
    const int idx = (t < n) ? t : (n - 1);
    hist_s[t] = film_hist[(size_t)b*L_ + idx];
    float rv = ratings[(size_t)b*L_ + idx];
    rat_s[t] = rv;
    r = (t < n) ? rv : 0.f;
  }
  if (t >= 448) {
    int fi = film_indices[b];
    xraw[256 + (t-448)] = emb[(size_t)fi*D_ + (t-448)];
  }

  // mean rating (block reduce; invalid lanes contribute 0)
  float s = r;
  #pragma unroll
  for (int off = 32; off; off >>= 1) s += __shfl_down(s, off);
  if (lane == 0) red[w] = s;
  __syncthreads();                           // (1) staging + mean partials
  const float mean_r = (red[0]+red[1]+red[2]+red[3]+red[4]+red[5]+red[6]+red[7]) / (float)n;
  const float mr1 = 0.1f - mean_r;

  // ---- pass 1: coalesced gather + stats + key writes ----
  float vmin = __builtin_inff(), vmax = -__builtin_inff(), vsum = 0.f;
  uint16_t* kout = sh.keys + lane*KP_U16 + w*28;
  #pragma unroll
  for (int ch = 0; ch < 7; ++ch) {
    if (ch*4 < cmax4) {                      // block-uniform guard
      float vv[4], wg[4];
      int   ll[4];
      #pragma unroll
      for (int j = 0; j < 4; ++j) ll[j] = w + 8*(ch*4 + j);
      #pragma unroll
      for (int j = 0; j < 4; ++j) vv[j] = emb[(size_t)hist_s[ll[j]]*D_ + lane];
      #pragma unroll
      for (int j = 0; j < 4; ++j) wg[j] = rat_s[ll[j]] + mr1;
      uint32_t kk[4];
      #pragma unroll
      for (int j = 0; j < 4; ++j) {
        const float wv = vv[j] * wg[j];
        vmin = fminf(vmin, wv); vmax = fmaxf(vmax, wv);
        vsum += (ll[j] < n) ? wv : 0.f;
        uint32_t u = __float_as_uint(wv);
        kk[j] = (u ^ (0x80000000u | (uint32_t)((int32_t)u >> 31))) >> 16;  // sortable 16b
      }
      uint2 pr;
      pr.x = kk[0] | (kk[1] << 16);
      pr.y = kk[2] | (kk[3] << 16);
      *(uint2*)(kout + ch*4) = pr;
    }
  }
  red3[t] = vmin; red3[512 + t] = vmax; red3[1024 + t] = vsum;
  __syncthreads();                           // (2) keys + stat partials ready

  // ---- stats reduce (t<192) into xraw[0..192) ----
  if (t < 64) {
    float m = red3[t];
    #pragma unroll
    for (int ww = 1; ww < 8; ++ww) m = fminf(m, red3[ww*64 + t]);
    xraw[t] = m;
  } else if (t < 128) {
    const int dd = t - 64;
    float m = red3[512 + dd];
    #pragma unroll
    for (int ww = 1; ww < 8; ++ww) m = fmaxf(m, red3[512 + ww*64 + dd]);
    xraw[64 + dd] = m;
  } else if (t < 192) {
    const int dd = t - 128;
    float m = red3[1024 + dd];
    #pragma unroll
    for (int ww = 1; ww < 8; ++ww) m += red3[1024 + ww*64 + dd];
    xraw[128 + dd] = m / (float)n;
  }

  // ---- pass 2: median select. sub = lane>>3, dim = w*8 + (lane&7) ----
  const int sub  = lane >> 3;
  const int dsel = w*8 + (lane & 7);
  const uint16_t* kp = sh.keys + dsel*KP_U16 + sub*28;
  uint32_t W[16];
  #pragma unroll
  for (int i = 0; i < 7; ++i) {
    uint2 v = *(const uint2*)(kp + 4*i);
    W[2*i] = v.x; W[2*i+1] = v.y;
  }
  W[14] = 0u; W[15] = 0u;

  // dual 16x16 bit-matrix transpose: plane for key-bit b is W[15-b];
  // key i sits at plane bit (15-(i>>1)) + 16*(i&1).
  #define XS(k, jj, m) { uint32_t tt = ((W[k] ^ (W[(k)|(jj)] >> (jj))) & (m)); \
                         W[k] ^= tt; W[(k)|(jj)] ^= (tt << (jj)); }
  XS(0,8,0x00FF00FFu) XS(1,8,0x00FF00FFu) XS(2,8,0x00FF00FFu) XS(3,8,0x00FF00FFu)
  XS(4,8,0x00FF00FFu) XS(5,8,0x00FF00FFu) XS(6,8,0x00FF00FFu) XS(7,8,0x00FF00FFu)
  XS(0,4,0x0F0F0F0Fu) XS(1,4,0x0F0F0F0Fu) XS(2,4,0x0F0F0F0Fu) XS(3,4,0x0F0F0F0Fu)
  XS(8,4,0x0F0F0F0Fu) XS(9,4,0x0F0F0F0Fu) XS(10,4,0x0F0F0F0Fu) XS(11,4,0x0F0F0F0Fu)
  XS(0,2,0x33333333u) XS(1,2,0x33333333u) XS(4,2,0x33333333u) XS(5,2,0x33333333u)
  XS(8,2,0x33333333u) XS(9,2,0x33333333u) XS(12,2,0x33333333u) XS(13,2,0x33333333u)
  XS(0,1,0x55555555u) XS(2,1,0x55555555u) XS(4,1,0x55555555u) XS(6,1,0x55555555u)
  XS(8,1,0x55555555u) XS(10,1,0x55555555u) XS(12,1,0x55555555u) XS(14,1,0x55555555u)
  #undef XS

  // bit-serial select of k-th smallest key (valid keys i in [0,c))
  const int c  = (n - sub + 7) >> 3;
  const int ce = (c + 1) >> 1, cf = c >> 1;
  uint32_t alive = ((1u << ce) - 1u) << (16 - ce);
  if (cf) alive |= ((1u << cf) - 1u) << (32 - cf);
  int k = (n - 1) >> 1;
  uint32_t prefix = 0;
  #pragma unroll
  for (int bb = 15; bb >= 0; --bb) {
    const uint32_t P = W[15 - bb];
    uint32_t z = alive & ~P;
    int cnt = __popc(z);
    cnt += __shfl_xor(cnt, 8);
    cnt += __shfl_xor(cnt, 16);
    cnt += __shfl_xor(cnt, 32);
    const bool zs = (k < cnt);
    alive  = zs ? z : (alive & P);
    k      = zs ? k : (k - cnt);
    prefix = zs ? prefix : (prefix | (1u << bb));
  }
  if (sub == 0) {
    uint32_t key32 = (prefix << 16) | 0x8000u;  // bucket midpoint
    float med = (prefix & 0x8000u) ? __uint_as_float(key32 ^ 0x80000000u)
                                   : __uint_as_float(~key32);
    xraw[192 + dsel] = med;
  }
  __syncthreads();                           // (3) xraw complete; keys dead

  // ---- ||ue|| partials (overlapped with h1 partials, same phase) ----
  {
    float v = (t < 256) ? xraw[t] : 0.f;
    float ss = v*v;
    #pragma unroll
    for (int off = 32; off; off >>= 1) ss += __shfl_down(ss, off);
    if (lane == 0) red[w] = ss;
  }

  // ---- MLP h1 partials: thread = (q = wave, jp = lane); j = 2*jp ----
  // A = dot over this q's 40 i's (raw x); B = fe-only portion (q>=6).
  {
    const int jp = lane, q = w;
    const float* Wp = W1 + 2*jp;
    v2f accA = {0.f, 0.f};
    #pragma unroll 8
    for (int ii = 0; ii < 40; ++ii) {
      const int i = q*40 + ii;
      v2f wv = *(const v2f*)(Wp + (size_t)i*128);
      const float xv = xraw[i];
      v2f xx = {xv, xv};
      accA = pk_fma(wv, xx, accA);
    }
    sh.m.phA[q*64 + jp] = accA;
    if (q >= 6) {
      v2f accB = {0.f, 0.f};
      if (q == 6) {
        #pragma unroll 8
        for (int ii = 16; ii < 40; ++ii) {
          const int i = 240 + ii;
          v2f wv = *(const v2f*)(Wp + (size_t)i*128);
          const float xv = xraw[i];
          v2f xx = {xv, xv};
          accB = pk_fma(wv, xx, accB);
        }
      } else {
        #pragma unroll 8
        for (int ii = 0; ii < 40; ++ii) {
          const int i = 280 + ii;
          v2f wv = *(const v2f*)(Wp + (size_t)i*128);
          const float xv = xraw[i];
          v2f xx = {xv, xv};
          accB = pk_fma(wv, xx, accB);
        }
      }
      sh.m.phB[(q-6)*64 + jp] = accB;
    }
  }
  __syncthreads();                           // (4) h1 partials + ss partials

  // ---- h1 combine (t<64): h1 = relu(b1 + rn*A + (1-rn)*B) ----
  if (t < 64) {
    const float rn = 1.0f / sqrtf(red[0]+red[1]+red[2]+red[3]+red[4]+red[5]+red[6]+red[7]);
    v2f sA = sh.m.phA[t];
    #pragma unroll
    for (int q = 1; q < 8; ++q) sA += sh.m.phA[q*64 + t];
    v2f sB = sh.m.phB[t] + sh.m.phB[64 + t];
    float h0 = b1[2*t]   + rn*sA.x + (1.f-rn)*sB.x;
    float h1 = b1[2*t+1] + rn*sA.y + (1.f-rn)*sB.y;
    sh.m.h1s[2*t]   = fmaxf(h0, 0.f);
    sh.m.h1s[2*t+1] = fmaxf(h1, 0.f);
  }
  __syncthreads();                           // (5) h1s ready

  // ---- h2 partials: thread = (q2 = t>>5 in [0,16), jp2 = t&31) ----
  {
    const int jp2 = t & 31, q2 = t >> 5;
    const float* Wp = W2 + 2*jp2;
    v2f acc = {0.f, 0.f};
    #pragma unroll
    for (int ii = 0; ii < 8; ++ii) {
      const int i = q2*8 + ii;
      v2f wv = *(const v2f*)(Wp + (size_t)i*64);
      const float xv = sh.m.h1s[i];
      v2f xx = {xv, xv};
      acc = pk_fma(wv, xx, acc);
    }
    sh.m.phA[q2*32 + jp2] = acc;             // phA reused (h1 partials dead)
  }
  __syncthreads();                           // (6) h2 partials

  // ---- h2 combine + final dot + sigmoid (t<32, wave 0, shfl-only) ----
  if (t < 32) {
    v2f sA = sh.m.phA[t];
    #pragma unroll
    for (int q = 1; q < 16; ++q) sA += sh.m.phA[q*32 + t];
    float g0 = fmaxf(b2[2*t]   + sA.x, 0.f);
    float g1 = fmaxf(b2[2*t+1] + sA.y, 0.f);
    float vv = g0*W3[2*t] + g1*W3[2*t+1];
    #pragma unroll
    for (int off = 16; off; off >>= 1) vv += __shfl_down(vv, off);
    if (t == 0) out[b] = 1.f / (1.f + __expf(-(vv + b3[0])));
  }
}

extern "C" void kernel_launch(void* const* d_in, const int* in_sizes, int n_in,
                              void* d_out, int out_size, void* d_ws, size_t ws_size,
                              hipStream_t stream) {
  const int*   film_hist = (const int*)d_in[0];
  const float* ratings   = (const float*)d_in[1];
  const int*   lengths   = (const int*)d_in[2];
  const int*   film_idx  = (const int*)d_in[3];
  const float* emb       = (const float*)d_in[4];
  const float* W1 = (const float*)d_in[5];
  const float* b1 = (const float*)d_in[6];
  const float* W2 = (const float*)d_in[7];
  const float* b2 = (const float*)d_in[8];
  const float* W3 = (const float*)d_in[9];
  const float* b3 = (const float*)d_in[10];

  fused_kernel<<<B_, 512, 0, stream>>>(film_hist, ratings, lengths, film_idx, emb,
                                       W1, b1, W2, b2, W3, b3, (float*)d_out);
}

// Round 8
// 60.505 us; speedup vs baseline: 1.3562x; 1.3562x over previous
//
#include <hip/hip_runtime.h>
#include <hip/hip_bf16.h>
#include <stdint.h>

// Recommender: B=4096 users, L=200 history, D=64 emb, F=100000 films.
// Single fused kernel, TWO users per 512-thread block (2048 blocks).
//  - staging/mean/normalize phases handle both users in one pass (u = t>>8)
//  - pass1 (scattered gather, 8 lanes/dim) + in-register keys + dual 16x16
//    bit-transpose + bit-serial popc median select: run for user A, then user
//    B, with NO barrier between -> waves drift and A-select overlaps B-gather.
//  - MLP 320->128->64->1: each W1/W2 element loaded once per block and FMA'd
//    into BOTH users' accumulators (halves weight L2 traffic per user).

#define B_ 4096
#define L_ 200
#define D_ 64
#define LPAD 224

__device__ __forceinline__ void user_pass(
    const float* __restrict__ emb,
    const int* hist_s, const float* rat_s,
    const int n, const float mr1, float* xrow,
    const int lane, const int sub, const int d)
{
  const int cmax  = (n + 7) >> 3;            // <=25, block-uniform
  const int cmax4 = (cmax + 3) & ~3;         // multiple of 4, <=28

  float vmin = __builtin_inff(), vmax = -__builtin_inff(), vsum = 0.f;
  uint32_t W[16];
  #pragma unroll
  for (int i = 0; i < 16; ++i) W[i] = 0u;

  const float* embd = emb + d;
  float vb[2][4], rb[2][4];
  #pragma unroll
  for (int j = 0; j < 4; ++j) {
    const int l = sub + 8*j;
    rb[0][j] = rat_s[l];
    vb[0][j] = embd[(size_t)hist_s[l] * D_];
  }
  #pragma unroll
  for (int ch = 0; ch < 7; ++ch) {
    const int cur = ch & 1, nxt = cur ^ 1;
    if ((ch+1)*4 < cmax4) {                  // block-uniform guard
      #pragma unroll
      for (int j = 0; j < 4; ++j) {
        const int l = sub + 8*((ch+1)*4 + j);
        rb[nxt][j] = rat_s[l];
        vb[nxt][j] = embd[(size_t)hist_s[l] * D_];
      }
    }
    if (ch*4 < cmax4) {                      // block-uniform guard
      uint32_t kk[4];
      #pragma unroll
      for (int j = 0; j < 4; ++j) {
        const int l = sub + 8*(ch*4 + j);
        const float wv = vb[cur][j] * (rb[cur][j] + mr1);
        vmin = fminf(vmin, wv); vmax = fmaxf(vmax, wv);
        vsum += (l < n) ? wv : 0.f;
        uint32_t u = __float_as_uint(wv);
        kk[j] = (u ^ (0x80000000u | (uint32_t)((int32_t)u >> 31))) >> 16;  // sortable 16b
      }
      W[2*ch]   = kk[0] | (kk[1] << 16);
      W[2*ch+1] = kk[2] | (kk[3] << 16);
    }
  }

  // combine min/max/sum across the 8 subs (lane bits 3,4,5)
  vmin = fminf(vmin, __shfl_xor(vmin, 8));
  vmin = fminf(vmin, __shfl_xor(vmin, 16));
  vmin = fminf(vmin, __shfl_xor(vmin, 32));
  vmax = fmaxf(vmax, __shfl_xor(vmax, 8));
  vmax = fmaxf(vmax, __shfl_xor(vmax, 16));
  vmax = fmaxf(vmax, __shfl_xor(vmax, 32));
  vsum += __shfl_xor(vsum, 8);
  vsum += __shfl_xor(vsum, 16);
  vsum += __shfl_xor(vsum, 32);

  // dual 16x16 bit-matrix transpose: plane for key-bit b is W[15-b];
  // key i sits at plane bit (15-(i>>1)) + 16*(i&1).
  #define XS(k, jj, m) { uint32_t tt = ((W[k] ^ (W[(k)|(jj)] >> (jj))) & (m)); \
                         W[k] ^= tt; W[(k)|(jj)] ^= (tt << (jj)); }
  XS(0,8,0x00FF00FFu) XS(1,8,0x00FF00FFu) XS(2,8,0x00FF00FFu) XS(3,8,0x00FF00FFu)
  XS(4,8,0x00FF00FFu) XS(5,8,0x00FF00FFu) XS(6,8,0x00FF00FFu) XS(7,8,0x00FF00FFu)
  XS(0,4,0x0F0F0F0Fu) XS(1,4,0x0F0F0F0Fu) XS(2,4,0x0F0F0F0Fu) XS(3,4,0x0F0F0F0Fu)
  XS(8,4,0x0F0F0F0Fu) XS(9,4,0x0F0F0F0Fu) XS(10,4,0x0F0F0F0Fu) XS(11,4,0x0F0F0F0Fu)
  XS(0,2,0x33333333u) XS(1,2,0x33333333u) XS(4,2,0x33333333u) XS(5,2,0x33333333u)
  XS(8,2,0x33333333u) XS(9,2,0x33333333u) XS(12,2,0x33333333u) XS(13,2,0x33333333u)
  XS(0,1,0x55555555u) XS(2,1,0x55555555u) XS(4,1,0x55555555u) XS(6,1,0x55555555u)
  XS(8,1,0x55555555u) XS(10,1,0x55555555u) XS(12,1,0x55555555u) XS(14,1,0x55555555u)
  #undef XS

  // bit-serial select of k-th smallest key (valid keys i in [0,c))
  const int c  = (n - sub + 7) >> 3;
  const int ce = (c + 1) >> 1, cf = c >> 1;
  uint32_t alive = ((1u << ce) - 1u) << (16 - ce);
  if (cf) alive |= ((1u << cf) - 1u) << (32 - cf);
  int k = (n - 1) >> 1;
  uint32_t prefix = 0;
  #pragma unroll
  for (int bb = 15; bb >= 0; --bb) {
    const uint32_t P = W[15 - bb];
    uint32_t z = alive & ~P;
    int cnt = __popc(z);
    cnt += __shfl_xor(cnt, 8);
    cnt += __shfl_xor(cnt, 16);
    cnt += __shfl_xor(cnt, 32);
    const bool zs = (k < cnt);
    alive  = zs ? z : (alive & P);
    k      = zs ? k : (k - cnt);
    prefix = zs ? prefix : (prefix | (1u << bb));
  }
  if (sub == 0) {
    uint32_t key32 = (prefix << 16) | 0x8000u;  // bucket midpoint
    float med = (prefix & 0x8000u) ? __uint_as_float(key32 ^ 0x80000000u)
                                   : __uint_as_float(~key32);
    xrow[d]       = vmin;
    xrow[64 + d]  = vmax;
    xrow[128 + d] = vsum / (float)n;
    xrow[192 + d] = med;
  }
}

__global__ __launch_bounds__(512) void fused_kernel(
    const int* __restrict__ film_hist,
    const float* __restrict__ ratings,
    const int* __restrict__ lengths,
    const int* __restrict__ film_indices,
    const float* __restrict__ emb,
    const float* __restrict__ W1, const float* __restrict__ b1,
    const float* __restrict__ W2, const float* __restrict__ b2,
    const float* __restrict__ W3, const float* __restrict__ b3,
    float* __restrict__ out)
{
  __shared__ int   hist_s[2][LPAD];
  __shared__ float rat_s[2][LPAD];
  __shared__ float red[8];
  __shared__ float xraw[2][320];             // per user: [ue(256) | fe(64)]
  __shared__ float ph[1024];                 // MLP partials [g][u][j]
  __shared__ float h1s[2][128];

  const int t = threadIdx.x;
  const int w = t >> 6;
  const int lane = t & 63;
  const int sub  = lane >> 3;
  const int d    = w*8 + (lane & 7);
  const int bA = 2*blockIdx.x, bB = bA + 1;
  const int nA = lengths[bA], nB = lengths[bB];

  // ---- stage both users (clamped) + fe; mean-rating partials ----
  {
    const int u  = t >> 8;                   // staging user
    const int tt = t & 255;
    const int nu = u ? nB : nA;
    float r = 0.f;
    if (tt < LPAD) {
      const int bu = bA + u;
      const int idx = (tt < nu) ? tt : (nu - 1);
      hist_s[u][tt] = film_hist[(size_t)bu*L_ + idx];
      float rv = ratings[(size_t)bu*L_ + idx];
      rat_s[u][tt] = rv;
      r = (tt < nu) ? rv : 0.f;
    }
    if (t >= 448) {
      const int dd = t - 448;
      xraw[0][256+dd] = emb[(size_t)film_indices[bA]*D_ + dd];
      xraw[1][256+dd] = emb[(size_t)film_indices[bB]*D_ + dd];
    }
    float s = r;
    #pragma unroll
    for (int off = 32; off; off >>= 1) s += __shfl_down(s, off);
    if (lane == 0) red[w] = s;
  }
  __syncthreads();                           // (1) staging + mean partials
  const float mr1A = 0.1f - (red[0]+red[1]+red[2]+red[3]) / (float)nA;
  const float mr1B = 0.1f - (red[4]+red[5]+red[6]+red[7]) / (float)nB;

  // ---- pass1 + select, user A then user B (no barrier between: waves
  //      drift, A-select VALU overlaps B-gather VMEM) ----
  user_pass(emb, hist_s[0], rat_s[0], nA, mr1A, xraw[0], lane, sub, d);
  user_pass(emb, hist_s[1], rat_s[1], nB, mr1B, xraw[1], lane, sub, d);
  __syncthreads();                           // (2) both xraw[.][0..256) ready

  // ---- L2-normalize both ue's in place (thread t -> element (t>>8, t&255)) ----
  {
    const int u  = t >> 8;
    const int tt = t & 255;
    float v = xraw[u][tt];
    float ss = v*v;
    #pragma unroll
    for (int off = 32; off; off >>= 1) ss += __shfl_down(ss, off);
    if (lane == 0) red[w] = ss;
    __syncthreads();                         // (3) sumsq partials
    const float rn = 1.0f / sqrtf(u ? (red[4]+red[5]+red[6]+red[7])
                                    : (red[0]+red[1]+red[2]+red[3]));
    xraw[u][tt] = v * rn;
  }
  __syncthreads();                           // (4) x ready for MLP

  // ---- MLP h1 partials: j = t&127, g = t>>7 owns i-slice [80g, 80g+80);
  //      each W1 element loaded ONCE, used for both users ----
  {
    const int j = t & 127, g = t >> 7;
    const float* Wp = W1 + (size_t)(g*80)*128 + j;
    const float* xa = xraw[0] + g*80;
    const float* xb = xraw[1] + g*80;
    float aA = 0.f, aB = 0.f;
    #pragma unroll 4
    for (int i = 0; i < 80; ++i) {
      const float wv = Wp[(size_t)i*128];
      aA += wv * xa[i];
      aB += wv * xb[i];
    }
    ph[g*256 + j]       = aA;
    ph[g*256 + 128 + j] = aB;
  }
  __syncthreads();                           // (5) h1 partials

  if (t < 256) {
    const int u = t >> 7, j = t & 127;
    const float h = b1[j] + ph[u*128 + j] + ph[256 + u*128 + j]
                          + ph[512 + u*128 + j] + ph[768 + u*128 + j];
    h1s[u][j] = fmaxf(h, 0.f);
  }
  __syncthreads();                           // (6) h1 ready

  // ---- MLP h2 partials: j = t&63, g = t>>6 owns i-slice [16g, 16g+16) ----
  {
    const int j = t & 63, g = t >> 6;
    const float* Wp = W2 + (size_t)(g*16)*64 + j;
    const float* ha = h1s[0] + g*16;
    const float* hb = h1s[1] + g*16;
    float aA = 0.f, aB = 0.f;
    #pragma unroll
    for (int i = 0; i < 16; ++i) {
      const float wv = Wp[(size_t)i*64];
      aA += wv * ha[i];
      aB += wv * hb[i];
    }
    ph[g*128 + j]      = aA;
    ph[g*128 + 64 + j] = aB;
  }
  __syncthreads();                           // (7) h2 partials

  // ---- h2 combine + final dot + sigmoid (t<128: wave0=userA, wave1=userB) ----
  if (t < 128) {
    const int u = t >> 6, j = t & 63;
    float h = b2[j];
    #pragma unroll
    for (int g = 0; g < 8; ++g) h += ph[g*128 + u*64 + j];
    h = fmaxf(h, 0.f);
    float vv = h * W3[j];
    #pragma unroll
    for (int off = 32; off; off >>= 1) vv += __shfl_down(vv, off);
    if (j == 0) out[bA + u] = 1.f / (1.f + __expf(-(vv + b3[0])));
  }
}

extern "C" void kernel_launch(void* const* d_in, const int* in_sizes, int n_in,
                              void* d_out, int out_size, void* d_ws, size_t ws_size,
                              hipStream_t stream) {
  const int*   film_hist = (const int*)d_in[0];
  const float* ratings   = (const float*)d_in[1];
  const int*   lengths   = (const int*)d_in[2];
  const int*   film_idx  = (const int*)d_in[3];
  const float* emb       = (const float*)d_in[4];
  const float* W1 = (const float*)d_in[5];
  const float* b1 = (const float*)d_in[6];
  const float* W2 = (const float*)d_in[7];
  const float* b2 = (const float*)d_in[8];
  const float* W3 = (const float*)d_in[9];
  const float* b3 = (const float*)d_in[10];

  fused_kernel<<<B_/2, 512, 0, stream>>>(film_hist, ratings, lengths, film_idx, emb,
                                         W1, b1, W2, b2, W3, b3, (float*)d_out);
}